// Round 1
// baseline (2729.273 us; speedup 1.0000x reference)
//
#include <hip/hip_runtime.h>
#include <hip/hip_bf16.h>
#include <math.h>

#define NB 32
#define HH 512
#define NIN 17
#define NF 12
#define TDIM 24
#define NTRI 3
#define GTOT 72
#define DTC 0.1f
#define SNLC 1.41421356237309515f
#define THETAC 0.5f
#define SCC 0.009765625f
#define EPSC 1e-6f

typedef __hip_bfloat16 bf16;

struct Args {
  const float *X, *Y, *A, *RH0;
  const float *Wihp, *Whhp, *Bp, *Wh2hp, *Wihh, *Wh2hh, *Lp, *We, *Be, *Wpe, *Bpe, *Wo, *Bo;
  bf16 *A0T;                                   // [NB][512][512]  A0T[b][j][i] = A[b][i][j], bf16
  float *WThh, *WTpp, *WTph, *WTe;             // [512][512] transposed (j-major)
  float *WTih_h, *WTih_p;                      // [17][512]
  float *rh;    // [3][NB][512] triple buffer (index g%3)
  float *rp;    // [2][NB][512]
  float *h1;    // [2][NB][512]  A_t @ rh_t
  float *Wp;    // [NB][512]     rowsum factor: A0@1 + sum sigma_s*FU_s
  float *FU;    // [72][NB][512] c^{-(s+1)}*DT*e_s*u_s
  float *FV;    // [72][NB][512] v_s = standardize(rh_s)
  float *alpha; // [NB][72]      v_s . rh_{g}  (written at P2(g-1) for use at P1(g))
  float *gpart; // [3][4][NB][512] GEMM partials (m, jc)
  float *hepart;// [8][NB][512]  W_e GEMV partials by j-chunk
  float *stats; // [2][NB][2]    (mean, sqrt(var+eps)) of rh_g at parity g&1
  float *sigv;  // [NB]          sigma_g = sum_j v_g[j]
  float *rwb;   // [2][NB]       reward (parity)
  float *aselb; // [2][NB][4]    actionSel (parity)
  float *slog;  // [NB][4]
  float *sprob; // [NB][4]
  float *out;
  int g;
};

__device__ inline float get_cdec(const Args& a) {
  float lv = fminf(a.Lp[0], 6.0f);
  float sig = 1.0f / (1.0f + expf(lv));   // sigmoid(-lv)
  float decay = fmaxf(-sig, -10.0f);
  return 1.0f + DTC * decay;
}

__device__ inline float redsum256(float v, float* red) {
  const int tid = threadIdx.x;
  red[tid] = v; __syncthreads();
  for (int s = 128; s > 0; s >>= 1) {
    if (tid < s) red[tid] += red[tid + s];
    __syncthreads();
  }
  float r = red[0]; __syncthreads();
  return r;
}

__device__ inline void stage_inp_all(const Args& a, float (*inpA)[NIN]) {
  const int g = a.g, t = g % TDIM, tri = g / TDIM;
  for (int e = threadIdx.x; e < NB * NIN; e += 256) {
    int b = e / NIN, k = e % NIN;
    float v;
    if (k < NF)       v = (t < 16) ? a.X[(size_t)((b*4 + (t >> 2))*NTRI + tri)*NF + k] : 0.0f;
    else if (k == NF) v = a.rwb[(g & 1)*NB + b];
    else              v = a.aselb[(size_t)((g & 1)*NB + b)*4 + (k - NF - 1)];
    inpA[b][k] = v;
  }
}

__device__ inline float calc_rhn(const Args& a, int b, int ii, const float* inp) {
  const int g = a.g;
  float gh2 = 0.f;
  #pragma unroll
  for (int q = 0; q < 4; q++) gh2 += a.gpart[(size_t)((0*4 + q)*NB + b)*HH + ii];
  float gh1 = 0.f;
  #pragma unroll
  for (int k = 0; k < NIN; k++) gh1 += a.WTih_h[k*HH + ii] * inp[k];
  float h1v = a.h1[(size_t)(g & 1)*NB*HH + b*HH + ii];
  float rhc = a.rh[(size_t)(g % 3)*NB*HH + b*HH + ii];
  float acth = fminf(fmaxf((SCC*h1v + gh1 + gh2 - THETAC)*SNLC, 0.f), 10.f);
  return 0.5f*rhc + 0.5f*acth;
}

__device__ inline float calc_rpn(const Args& a, int b, int ii, const float* inp) {
  const int g = a.g;
  float gp2 = 0.f, gp3 = 0.f;
  #pragma unroll
  for (int q = 0; q < 4; q++) {
    gp2 += a.gpart[(size_t)((1*4 + q)*NB + b)*HH + ii];
    gp3 += a.gpart[(size_t)((2*4 + q)*NB + b)*HH + ii];
  }
  float gp1 = 0.f;
  #pragma unroll
  for (int k = 0; k < NIN; k++) gp1 += a.WTih_p[k*HH + ii] * inp[k];
  float rpc = a.rp[(size_t)(g & 1)*NB*HH + b*HH + ii];
  float actp = gp1 + gp2 + gp3 + a.Bp[ii];
  return 0.5f*rpc + 0.5f*fmaxf(actp, 0.f);
}

// ---------- prep: tiled transpose (A0 -> bf16, weights -> f32) ----------
__global__ __launch_bounds__(256) void k_prep_t(Args a) {
  __shared__ float tile[32][33];
  const int bid = blockIdx.x, tid = threadIdx.x;
  const float* src; float* dstF = nullptr; bf16* dstB = nullptr; int tIdx;
  if (bid < 8192) {
    int b = bid >> 8; tIdx = bid & 255;
    src = a.A + (size_t)b*HH*HH;
    dstB = a.A0T + (size_t)b*HH*HH;
  } else {
    int m = (bid - 8192) >> 8; tIdx = bid & 255;
    src  = (m == 0) ? a.Wh2hh : (m == 1) ? a.Whhp : (m == 2) ? a.Wh2hp : a.We;
    dstF = (m == 0) ? a.WThh  : (m == 1) ? a.WTpp : (m == 2) ? a.WTph  : a.WTe;
  }
  const int tx = tIdx & 15, ty = tIdx >> 4;
  for (int k = 0; k < 4; k++) {
    int e = tid + k*256, r = e >> 5, c = e & 31;
    tile[r][c] = src[(size_t)(ty*32 + r)*HH + tx*32 + c];
  }
  __syncthreads();
  for (int k = 0; k < 4; k++) {
    int e = tid + k*256, r = e >> 5, c = e & 31;
    float v = tile[c][r];
    size_t off = (size_t)(tx*32 + r)*HH + ty*32 + c;
    if (dstB) dstB[off] = __float2bfloat16(v);
    else      dstF[off] = v;
  }
}

// ---------- prep: rowsums, init state, small transposes, zeros ----------
__global__ __launch_bounds__(256) void k_prep_i(Args a) {
  __shared__ float red[256];
  const int bid = blockIdx.x, tid = threadIdx.x;
  if (bid < 64) {
    const int b = bid >> 1;
    const int i = (bid & 1)*256 + tid;
    const bf16* col = a.A0T + (size_t)b*HH*HH + i;
    float s0 = 0.f, s1 = 0.f;
    for (int j = 0; j < HH; j += 2) {
      s0 += (float)col[(size_t)j*HH];
      s1 += (float)col[(size_t)(j + 1)*HH];
    }
    a.Wp[b*HH + i] = s0 + s1;
  } else if (bid < 96) {
    const int b = bid - 64;
    const float* r0 = a.RH0 + (size_t)b*HH;   // rh_init[b, 0, :]
    float s = 0.f;
    for (int ii = tid; ii < HH; ii += 256) { float v = r0[ii]; a.rh[b*HH + ii] = v; s += v; }
    float m = redsum256(s, red) / (float)HH;
    float s2 = 0.f;
    for (int ii = tid; ii < HH; ii += 256) { float d = r0[ii] - m; s2 += d*d; }
    float var = redsum256(s2, red) / (float)HH;
    if (tid == 0) { a.stats[b*2] = m; a.stats[b*2 + 1] = sqrtf(var + EPSC); }
  } else if (bid == 96) {
    for (int e = tid; e < NB*HH; e += 256) a.rp[e] = 0.f;
    if (tid < NB*4) { a.slog[tid] = 0.f; a.sprob[tid] = 0.f; a.aselb[tid] = 0.f; }
    if (tid < NB) a.rwb[tid] = 0.f;
  } else {
    const int m = bid - 97;
    const float* W = m ? a.Wihp : a.Wihh;
    float* D = m ? a.WTih_p : a.WTih_h;
    for (int e = tid; e < NIN*HH; e += 256) {
      int j = e / HH, i = e % HH;
      D[j*HH + i] = W[i*NIN + j];
    }
  }
}

// ---------- per-step P1: A0 matvec + history + finalize(g-1) ; 3 shared GEMMs ----------
__global__ __launch_bounds__(256) void k_p1(Args a) {
  const int g = a.g;
  const int bid = blockIdx.x;
  const int tid = threadIdx.x;
  __shared__ float rh_l[HH];
  __shared__ float al_l[GTOT];
  __shared__ float red[256];
  __shared__ float vl[128*33];
  const float cdec = get_cdec(a);
  if (bid < 64) {
    const int b = bid >> 1;
    const int i = (bid & 1)*256 + tid;
    const float* rhc = a.rh + (size_t)(g % 3)*NB*HH + b*HH;
    rh_l[tid]       = rhc[tid];
    rh_l[tid + 256] = rhc[tid + 256];
    if (tid < g) al_l[tid] = a.alpha[b*GTOT + tid];
    __syncthreads();
    float fu_local = 0.f;
    if (g > 0) {
      // e_{g-1} = 0.01*sigmoid(W_pe . relu(sum hepart + b_e) + b_pe)
      float part = 0.f;
      for (int ii = tid; ii < HH; ii += 256) {
        float hv = a.Be[ii];
        #pragma unroll
        for (int q = 0; q < 8; q++) hv += a.hepart[(size_t)(q*NB + b)*HH + ii];
        part += a.Wpe[ii] * fmaxf(hv, 0.f);
      }
      float pe = redsum256(part, red) + a.Bpe[0];
      float ev = 0.01f / (1.0f + expf(-pe));
      const float m_cur  = a.stats[(g & 1)*NB*2 + b*2];
      const float sd_cur = a.stats[(g & 1)*NB*2 + b*2 + 1];
      const float m_pre  = a.stats[((g + 1) & 1)*NB*2 + b*2];
      const float sd_pre = a.stats[((g + 1) & 1)*NB*2 + b*2 + 1];
      const float cpow_prev = powf(cdec, (float)(g - 1));
      float wv   = cpow_prev * a.Wp[b*HH + i];
      float tmp  = (a.h1[(size_t)((g + 1) & 1)*NB*HH + b*HH + i] - m_pre*wv) / sd_pre;
      float post = (rh_l[i] - m_cur) / sd_cur;
      float coef = powf(cdec, -(float)g) * DTC * ev;
      fu_local = coef * (post - tmp);
      a.FU[(size_t)((g - 1)*NB + b)*HH + i] = fu_local;
      a.Wp[b*HH + i] += a.sigv[b] * fu_local;
    }
    // A0 column dot + low-rank history
    const bf16* colp = a.A0T + (size_t)b*HH*HH + i;
    float c0 = 0.f, c1 = 0.f, c2 = 0.f, c3 = 0.f;
    for (int j = 0; j < HH; j += 4) {
      c0 += (float)colp[(size_t)(j    )*HH] * rh_l[j];
      c1 += (float)colp[(size_t)(j + 1)*HH] * rh_l[j + 1];
      c2 += (float)colp[(size_t)(j + 2)*HH] * rh_l[j + 2];
      c3 += (float)colp[(size_t)(j + 3)*HH] * rh_l[j + 3];
    }
    float acc = (c0 + c1) + (c2 + c3);
    float hist = 0.f;
    for (int s = 0; s < g - 1; s++) hist += al_l[s] * a.FU[(size_t)(s*NB + b)*HH + i];
    if (g > 0) hist += al_l[g - 1] * fu_local;
    float cpow = powf(cdec, (float)g);
    a.h1[(size_t)(g & 1)*NB*HH + b*HH + i] = cpow * (acc + hist);
  } else {
    // batch-tiled GEMM partials: m0 gh2 = W_h2h_hpc @ rp ; m1 gp2 = W_hh_pfc @ rp ; m2 gp3 = W_h2h_pfc @ rh
    const int gid = bid - 64;
    const int m = gid >> 5, sub = gid & 31, ic = sub >> 2, jc = sub & 3;
    const int j0 = jc*128, i0 = ic*64;
    const float* WT  = (m == 0) ? a.WThh : (m == 1) ? a.WTpp : a.WTph;
    const float* vec = (m == 2) ? (a.rh + (size_t)(g % 3)*NB*HH) : (a.rp + (size_t)(g & 1)*NB*HH);
    for (int k = 0; k < 16; k++) {
      int e = tid + k*256;
      int b2 = e >> 7, jl = e & 127;
      vl[jl*33 + b2] = vec[(size_t)b2*HH + j0 + jl];
    }
    __syncthreads();
    const int bb = tid & 31, ig = tid >> 5;
    const int ii = i0 + ig*8;
    float acc[8] = {0.f,0.f,0.f,0.f,0.f,0.f,0.f,0.f};
    for (int jl = 0; jl < 128; jl++) {
      float v = vl[jl*33 + bb];
      const float* wr = WT + (size_t)(j0 + jl)*HH + ii;
      #pragma unroll
      for (int q = 0; q < 8; q++) acc[q] += wr[q] * v;
    }
    float* dst = a.gpart + (size_t)((m*4 + jc)*NB + bb)*HH + ii;
    #pragma unroll
    for (int q = 0; q < 8; q++) dst[q] = acc[q];
  }
}

// ---------- per-step P2: state update / stats / logits / V,sigma / W_e partials / alphas ----------
__global__ __launch_bounds__(256) void k_p2(Args a) {
  const int g = a.g;
  const int bid = blockIdx.x;
  const int tid = threadIdx.x;
  const int t = g % TDIM, tri = g / TDIM;
  __shared__ float inpA[NB][NIN];
  __shared__ float rhn_l[HH];
  __shared__ float red[256];
  __shared__ float vl[64*33];
  stage_inp_all(a, inpA);
  __syncthreads();
  if (bid < 32) {
    const int b = bid;
    const float m_cur  = a.stats[(g & 1)*NB*2 + b*2];
    const float sd_cur = a.stats[(g & 1)*NB*2 + b*2 + 1];
    float pfv = 0.f, psum = 0.f, lg0 = 0.f, lg1 = 0.f, lg2 = 0.f, lg3 = 0.f;
    for (int kk = 0; kk < 2; kk++) {
      int ii = tid + kk*256;
      float rhn = calc_rhn(a, b, ii, inpA[b]);
      float rpn = calc_rpn(a, b, ii, inpA[b]);
      rhn_l[ii] = rhn;
      a.rh[(size_t)((g + 1) % 3)*NB*HH + b*HH + ii] = rhn;
      a.rp[(size_t)((g + 1) & 1)*NB*HH + b*HH + ii] = (t == 23) ? 0.f : rpn;
      float rhc = a.rh[(size_t)(g % 3)*NB*HH + b*HH + ii];
      float fv = (rhc - m_cur) / sd_cur;
      a.FV[(size_t)(g*NB + b)*HH + ii] = fv;
      pfv += fv; psum += rhn;
      lg0 += a.Wo[0*HH + ii]*rpn; lg1 += a.Wo[1*HH + ii]*rpn;
      lg2 += a.Wo[2*HH + ii]*rpn; lg3 += a.Wo[3*HH + ii]*rpn;
    }
    __syncthreads();
    float sig = redsum256(pfv, red);
    float m2  = redsum256(psum, red) / (float)HH;
    float pvar = 0.f;
    for (int kk = 0; kk < 2; kk++) { float d = rhn_l[tid + kk*256] - m2; pvar += d*d; }
    float sd2 = sqrtf(redsum256(pvar, red) / (float)HH + EPSC);
    float L0 = redsum256(lg0, red) + a.Bo[0];
    float L1 = redsum256(lg1, red) + a.Bo[1];
    float L2 = redsum256(lg2, red) + a.Bo[2];
    float L3 = redsum256(lg3, red) + a.Bo[3];
    if (tid == 0) {
      a.sigv[b] = sig;
      a.stats[((g + 1) & 1)*NB*2 + b*2] = m2;
      a.stats[((g + 1) & 1)*NB*2 + b*2 + 1] = sd2;
      float sl0 = a.slog[b*4], sl1 = a.slog[b*4+1], sl2 = a.slog[b*4+2], sl3 = a.slog[b*4+3];
      float sp0 = a.sprob[b*4], sp1 = a.sprob[b*4+1], sp2 = a.sprob[b*4+2], sp3 = a.sprob[b*4+3];
      if (t >= 12 && t < 20) {
        sl0 += L0; sl1 += L1; sl2 += L2; sl3 += L3;
        float mx = fmaxf(fmaxf(L0, L1), fmaxf(L2, L3));
        float e0 = expf(L0 - mx), e1 = expf(L1 - mx), e2 = expf(L2 - mx), e3 = expf(L3 - mx);
        float es = e0 + e1 + e2 + e3;
        sp0 += e0/es; sp1 += e1/es; sp2 += e2/es; sp3 += e3/es;
      }
      float rwn, as0, as1, as2, as3;
      if (t == 19) {
        int am = 0; float bv = sp0;
        if (sp1 > bv) { bv = sp1; am = 1; }
        if (sp2 > bv) { bv = sp2; am = 2; }
        if (sp3 > bv) { bv = sp3; am = 3; }
        float corr = a.Y[(size_t)(b*4 + am)*NTRI + tri];
        rwn = (corr > 0.9f) ? 1.f : -1.f;
        as0 = (am == 0) ? 1.f : 0.f; as1 = (am == 1) ? 1.f : 0.f;
        as2 = (am == 2) ? 1.f : 0.f; as3 = (am == 3) ? 1.f : 0.f;
      } else {
        rwn = a.rwb[(g & 1)*NB + b];
        const float* ap = a.aselb + (size_t)((g & 1)*NB + b)*4;
        as0 = ap[0]; as1 = ap[1]; as2 = ap[2]; as3 = ap[3];
      }
      if (t == 23) {
        float* o = a.out + (size_t)tri*NB*4 + b*4;
        o[0] = sl0/8.f; o[1] = sl1/8.f; o[2] = sl2/8.f; o[3] = sl3/8.f;
        sl0 = sl1 = sl2 = sl3 = 0.f; sp0 = sp1 = sp2 = sp3 = 0.f;
        rwn = 0.f; as0 = as1 = as2 = as3 = 0.f;
      }
      a.slog[b*4] = sl0; a.slog[b*4+1] = sl1; a.slog[b*4+2] = sl2; a.slog[b*4+3] = sl3;
      a.sprob[b*4] = sp0; a.sprob[b*4+1] = sp1; a.sprob[b*4+2] = sp2; a.sprob[b*4+3] = sp3;
      a.rwb[((g + 1) & 1)*NB + b] = rwn;
      float* an = a.aselb + (size_t)(((g + 1) & 1)*NB + b)*4;
      an[0] = as0; an[1] = as1; an[2] = as2; an[3] = as3;
    }
  } else if (bid < 64) {
    // W_e GEMV partials over j-chunks (true rp_new recomputed; no t==23 reset here)
    const int hb = bid - 32;
    const int jc = hb >> 2, icc = hb & 3;
    const int j0 = jc*64;
    for (int k = 0; k < 8; k++) {
      int e = tid + k*256;
      int b2 = e >> 6, jl = e & 63;
      vl[jl*33 + b2] = calc_rpn(a, b2, j0 + jl, inpA[b2]);
    }
    __syncthreads();
    const int bb = tid & 31, ig = tid >> 5;
    const int ii = icc*128 + ig*16;
    float acc[16];
    #pragma unroll
    for (int q = 0; q < 16; q++) acc[q] = 0.f;
    for (int jl = 0; jl < 64; jl++) {
      float v = vl[jl*33 + bb];
      const float* wr = a.WTe + (size_t)(j0 + jl)*HH + ii;
      #pragma unroll
      for (int q = 0; q < 16; q++) acc[q] += wr[q] * v;
    }
    float* dst = a.hepart + (size_t)(jc*NB + bb)*HH + ii;
    #pragma unroll
    for (int q = 0; q < 16; q++) dst[q] = acc[q];
  } else {
    // alpha dots for next step: alpha[s] = v_s . rh_{g+1}, s = 0..g  (s==g computed directly)
    const int b = bid - 64;
    for (int ii = tid; ii < HH; ii += 256) rhn_l[ii] = calc_rhn(a, b, ii, inpA[b]);
    __syncthreads();
    const int lane = tid & 63, wv = tid >> 6;
    const float m_cur  = a.stats[(g & 1)*NB*2 + b*2];
    const float sd_cur = a.stats[(g & 1)*NB*2 + b*2 + 1];
    const float* rhc = a.rh + (size_t)(g % 3)*NB*HH + b*HH;
    for (int s = wv; s <= g; s += 4) {
      float p = 0.f;
      if (s < g) {
        const float* V = a.FV + (size_t)(s*NB + b)*HH;
        for (int jj = lane; jj < HH; jj += 64) p += V[jj] * rhn_l[jj];
      } else {
        for (int jj = lane; jj < HH; jj += 64) p += ((rhc[jj] - m_cur)/sd_cur) * rhn_l[jj];
      }
      #pragma unroll
      for (int off = 32; off > 0; off >>= 1) p += __shfl_down(p, off);
      if (lane == 0) a.alpha[b*GTOT + s] = p;
    }
  }
}

extern "C" void kernel_launch(void* const* d_in, const int* in_sizes, int n_in,
                              void* d_out, int out_size, void* d_ws, size_t ws_size,
                              hipStream_t stream) {
  (void)in_sizes; (void)n_in; (void)out_size; (void)ws_size;
  Args a;
  a.X     = (const float*)d_in[0];
  a.Y     = (const float*)d_in[1];
  a.A     = (const float*)d_in[2];
  a.RH0   = (const float*)d_in[3];
  a.Wihp  = (const float*)d_in[5];
  a.Whhp  = (const float*)d_in[6];
  a.Bp    = (const float*)d_in[7];
  a.Wh2hp = (const float*)d_in[8];
  a.Wihh  = (const float*)d_in[9];
  a.Wh2hh = (const float*)d_in[10];
  a.Lp    = (const float*)d_in[11];
  a.We    = (const float*)d_in[12];
  a.Be    = (const float*)d_in[13];
  a.Wpe   = (const float*)d_in[14];
  a.Bpe   = (const float*)d_in[15];
  a.Wo    = (const float*)d_in[16];
  a.Bo    = (const float*)d_in[17];
  char* w = (char*)d_ws;
  auto take = [&](size_t n) { char* p = w; w += (n + 255) & ~(size_t)255; return p; };
  a.A0T    = (bf16*)take((size_t)NB*HH*HH*sizeof(bf16));
  a.WThh   = (float*)take((size_t)HH*HH*4);
  a.WTpp   = (float*)take((size_t)HH*HH*4);
  a.WTph   = (float*)take((size_t)HH*HH*4);
  a.WTe    = (float*)take((size_t)HH*HH*4);
  a.WTih_h = (float*)take((size_t)NIN*HH*4);
  a.WTih_p = (float*)take((size_t)NIN*HH*4);
  a.rh     = (float*)take((size_t)3*NB*HH*4);
  a.rp     = (float*)take((size_t)2*NB*HH*4);
  a.h1     = (float*)take((size_t)2*NB*HH*4);
  a.Wp     = (float*)take((size_t)NB*HH*4);
  a.FU     = (float*)take((size_t)GTOT*NB*HH*4);
  a.FV     = (float*)take((size_t)GTOT*NB*HH*4);
  a.alpha  = (float*)take((size_t)NB*GTOT*4);
  a.gpart  = (float*)take((size_t)12*NB*HH*4);
  a.hepart = (float*)take((size_t)8*NB*HH*4);
  a.stats  = (float*)take((size_t)2*NB*2*4);
  a.sigv   = (float*)take((size_t)NB*4);
  a.rwb    = (float*)take((size_t)2*NB*4);
  a.aselb  = (float*)take((size_t)2*NB*4*4);
  a.slog   = (float*)take((size_t)NB*4*4);
  a.sprob  = (float*)take((size_t)NB*4*4);
  a.out    = (float*)d_out;
  a.g = 0;
  k_prep_t<<<dim3(9216), dim3(256), 0, stream>>>(a);
  k_prep_i<<<dim3(99),   dim3(256), 0, stream>>>(a);
  for (int g = 0; g < GTOT; g++) {
    a.g = g;
    k_p1<<<dim3(160), dim3(256), 0, stream>>>(a);
    k_p2<<<dim3(96),  dim3(256), 0, stream>>>(a);
  }
}

// Round 2
// 2021.703 us; speedup vs baseline: 1.3500x; 1.3500x over previous
//
#include <hip/hip_runtime.h>
#include <hip/hip_bf16.h>
#include <math.h>

#define NB 32
#define HH 512
#define NIN 17
#define NF 12
#define TDIM 24
#define NTRI 3
#define GTOT 72
#define DTC 0.1f
#define SNLC 1.41421356237309515f
#define THETAC 0.5f
#define SCC 0.009765625f
#define EPSC 1e-6f

typedef __hip_bfloat16 bf16;
typedef __attribute__((ext_vector_type(8))) unsigned short ushort8v;

struct Args {
  const float *X, *Y, *A, *RH0;
  const float *Wihp, *Whhp, *Bp, *Wh2hp, *Wihh, *Wh2hh, *Lp, *We, *Be, *Wpe, *Bpe, *Wo, *Bo;
  bf16 *A0T;                                   // [NB][512][512]  A0T[b][j][i] = A[b][i][j], bf16
  float *WThh, *WTpp, *WTph, *WTe;             // [512][512] transposed (j-major)
  float *WTih_h, *WTih_p;                      // [17][512]
  float *rh;    // [3][NB][512] triple buffer (index g%3)
  float *rp;    // [2][NB][512]
  float *h1;    // [2][NB][512]  A_t @ rh_t
  float *Wp;    // [NB][512]     rowsum factor: A0@1 + sum sigma_s*FU_s
  float *FU;    // [72][NB][512] c^{-(s+1)}*DT*e_s*u_s
  float *FV;    // [72][NB][512] v_s = standardize(rh_s)
  float *alpha; // [NB][72]      v_s . rh_{g}  (written at P2(g-1) for use at P1(g))
  float *gpart; // [3][4][NB][512] GEMM partials (m, jc)
  float *hepart;// [8][NB][512]  W_e GEMV partials by j-chunk
  float *stats; // [2][NB][2]    (mean, sqrt(var+eps)) of rh_g at parity g&1
  float *sigv;  // [NB]
  float *rwb;   // [2][NB]
  float *aselb; // [2][NB][4]
  float *slog;  // [NB][4]
  float *sprob; // [NB][4]
  float *out;
  int g;
};

__device__ inline float get_cdec(const Args& a) {
  float lv = fminf(a.Lp[0], 6.0f);
  float sig = 1.0f / (1.0f + expf(lv));   // sigmoid(-lv)
  float decay = fmaxf(-sig, -10.0f);
  return 1.0f + DTC * decay;
}

// fast block sum: wave shuffle + 4-slot LDS (256 threads)
__device__ inline float blocksum(float v, float* lds4) {
  const int lane = threadIdx.x & 63, wv = threadIdx.x >> 6;
  #pragma unroll
  for (int off = 32; off > 0; off >>= 1) v += __shfl_down(v, off, 64);
  if (lane == 0) lds4[wv] = v;
  __syncthreads();
  float r = lds4[0] + lds4[1] + lds4[2] + lds4[3];
  __syncthreads();
  return r;
}

__device__ inline void stage_inp_all(const Args& a, float (*inpA)[NIN]) {
  const int g = a.g, t = g % TDIM, tri = g / TDIM;
  for (int e = threadIdx.x; e < NB * NIN; e += 256) {
    int b = e / NIN, k = e % NIN;
    float v;
    if (k < NF)       v = (t < 16) ? a.X[(size_t)((b*4 + (t >> 2))*NTRI + tri)*NF + k] : 0.0f;
    else if (k == NF) v = a.rwb[(g & 1)*NB + b];
    else              v = a.aselb[(size_t)((g & 1)*NB + b)*4 + (k - NF - 1)];
    inpA[b][k] = v;
  }
}

__device__ inline float calc_rhn(const Args& a, int b, int ii, const float* inp) {
  const int g = a.g;
  float gh2 = 0.f;
  #pragma unroll
  for (int q = 0; q < 4; q++) gh2 += a.gpart[(size_t)((0*4 + q)*NB + b)*HH + ii];
  float gh1 = 0.f;
  #pragma unroll
  for (int k = 0; k < NIN; k++) gh1 += a.WTih_h[k*HH + ii] * inp[k];
  float h1v = a.h1[(size_t)(g & 1)*NB*HH + b*HH + ii];
  float rhc = a.rh[(size_t)(g % 3)*NB*HH + b*HH + ii];
  float acth = fminf(fmaxf((SCC*h1v + gh1 + gh2 - THETAC)*SNLC, 0.f), 10.f);
  return 0.5f*rhc + 0.5f*acth;
}

__device__ inline float calc_rpn(const Args& a, int b, int ii, const float* inp) {
  const int g = a.g;
  float gp2 = 0.f, gp3 = 0.f;
  #pragma unroll
  for (int q = 0; q < 4; q++) {
    gp2 += a.gpart[(size_t)((1*4 + q)*NB + b)*HH + ii];
    gp3 += a.gpart[(size_t)((2*4 + q)*NB + b)*HH + ii];
  }
  float gp1 = 0.f;
  #pragma unroll
  for (int k = 0; k < NIN; k++) gp1 += a.WTih_p[k*HH + ii] * inp[k];
  float rpc = a.rp[(size_t)(g & 1)*NB*HH + b*HH + ii];
  float actp = gp1 + gp2 + gp3 + a.Bp[ii];
  return 0.5f*rpc + 0.5f*fmaxf(actp, 0.f);
}

// ---------- prep: tiled transpose (A0 -> bf16, weights -> f32) ----------
__global__ __launch_bounds__(256) void k_prep_t(Args a) {
  __shared__ float tile[32][33];
  const int bid = blockIdx.x, tid = threadIdx.x;
  const float* src; float* dstF = nullptr; bf16* dstB = nullptr; int tIdx;
  if (bid < 8192) {
    int b = bid >> 8; tIdx = bid & 255;
    src = a.A + (size_t)b*HH*HH;
    dstB = a.A0T + (size_t)b*HH*HH;
  } else {
    int m = (bid - 8192) >> 8; tIdx = bid & 255;
    src  = (m == 0) ? a.Wh2hh : (m == 1) ? a.Whhp : (m == 2) ? a.Wh2hp : a.We;
    dstF = (m == 0) ? a.WThh  : (m == 1) ? a.WTpp : (m == 2) ? a.WTph  : a.WTe;
  }
  const int tx = tIdx & 15, ty = tIdx >> 4;
  for (int k = 0; k < 4; k++) {
    int e = tid + k*256, r = e >> 5, c = e & 31;
    tile[r][c] = src[(size_t)(ty*32 + r)*HH + tx*32 + c];
  }
  __syncthreads();
  for (int k = 0; k < 4; k++) {
    int e = tid + k*256, r = e >> 5, c = e & 31;
    float v = tile[c][r];
    size_t off = (size_t)(tx*32 + r)*HH + ty*32 + c;
    if (dstB) dstB[off] = __float2bfloat16(v);
    else      dstF[off] = v;
  }
}

// ---------- prep: rowsums (wide), init state, small transposes, zeros ----------
__global__ __launch_bounds__(256) void k_prep_i(Args a) {
  __shared__ float sacc[16][128];
  __shared__ float lds4[4];
  const int bid = blockIdx.x, tid = threadIdx.x;
  if (bid < 128) {
    // Wp rowsum of A0T columns, wide loads
    const int b = bid >> 2, q = bid & 3, i0 = q*128;
    const int jg = tid >> 4, il = (tid & 15)*8;
    const ushort8v* ap = (const ushort8v*)(a.A0T + (size_t)b*HH*HH);
    const int ci = (i0 + il) >> 3;
    float acc[8] = {0.f,0.f,0.f,0.f,0.f,0.f,0.f,0.f};
    for (int it = 0; it < 32; it++) {
      int j = jg*32 + it;
      ushort8v u = ap[(size_t)j*64 + ci];
      #pragma unroll
      for (int qq = 0; qq < 8; qq++)
        acc[qq] += __uint_as_float(((unsigned)u[qq]) << 16);
    }
    ((float4*)&sacc[jg][il])[0] = make_float4(acc[0],acc[1],acc[2],acc[3]);
    ((float4*)&sacc[jg][il])[1] = make_float4(acc[4],acc[5],acc[6],acc[7]);
    __syncthreads();
    if (tid < 128) {
      float s = 0.f;
      #pragma unroll
      for (int r = 0; r < 16; r++) s += sacc[r][tid];
      a.Wp[b*HH + i0 + tid] = s;
    }
  } else if (bid < 160) {
    const int b = bid - 128;
    const float* r0 = a.RH0 + (size_t)b*HH;   // rh_init[b, 0, :]
    float s = 0.f, s2 = 0.f;
    for (int ii = tid; ii < HH; ii += 256) {
      float v = r0[ii]; a.rh[b*HH + ii] = v; s += v; s2 += v*v;
    }
    float m  = blocksum(s, lds4) / (float)HH;
    float e2 = blocksum(s2, lds4) / (float)HH;
    if (tid == 0) { a.stats[b*2] = m; a.stats[b*2 + 1] = sqrtf(e2 - m*m + EPSC); }
  } else if (bid == 160) {
    for (int e = tid; e < NB*HH; e += 256) a.rp[e] = 0.f;
    if (tid < NB*4) { a.slog[tid] = 0.f; a.sprob[tid] = 0.f; a.aselb[tid] = 0.f; }
    if (tid < NB) a.rwb[tid] = 0.f;
  } else {
    const int m = bid - 161;
    const float* W = m ? a.Wihp : a.Wihh;
    float* D = m ? a.WTih_p : a.WTih_h;
    for (int e = tid; e < NIN*HH; e += 256) {
      int j = e / HH, i = e % HH;
      D[j*HH + i] = W[i*NIN + j];
    }
  }
}

// ---------- per-step P1: wide A0 matvec + history + finalize(g-1) ; 3 shared GEMMs ----------
__global__ __launch_bounds__(256) void k_p1(Args a) {
  const int g = a.g;
  const int bid = blockIdx.x;
  const int tid = threadIdx.x;
  __shared__ float rh_l[HH];
  __shared__ float al_l[GTOT];
  __shared__ float sacc[16][128];
  __shared__ float lds4[4];
  __shared__ float vl[128*33];
  const float cdec = get_cdec(a);
  if (bid < 128) {
    const int b = bid >> 2, q = bid & 3, i0 = q*128;
    const float* rhc = a.rh + (size_t)(g % 3)*NB*HH + b*HH;
    rh_l[tid]       = rhc[tid];
    rh_l[tid + 256] = rhc[tid + 256];
    if (tid < g) al_l[tid] = a.alpha[b*GTOT + tid];
    __syncthreads();
    float ev = 0.f;
    if (g > 0) {
      float part = 0.f;
      for (int ii = tid; ii < HH; ii += 256) {
        float hv = a.Be[ii];
        #pragma unroll
        for (int qq = 0; qq < 8; qq++) hv += a.hepart[(size_t)(qq*NB + b)*HH + ii];
        part += a.Wpe[ii] * fmaxf(hv, 0.f);
      }
      float pe = blocksum(part, lds4) + a.Bpe[0];
      ev = 0.01f / (1.0f + expf(-pe));
    }
    // wide A0T matvec: 16 j-groups x (16 threads x 8 cols)
    const int jg = tid >> 4, il = (tid & 15)*8;
    const ushort8v* ap = (const ushort8v*)(a.A0T + (size_t)b*HH*HH);
    const int ci = (i0 + il) >> 3;
    float acc[8] = {0.f,0.f,0.f,0.f,0.f,0.f,0.f,0.f};
    for (int it = 0; it < 32; it++) {
      int j = jg*32 + it;
      ushort8v u = ap[(size_t)j*64 + ci];
      float w = rh_l[j];
      #pragma unroll
      for (int qq = 0; qq < 8; qq++)
        acc[qq] = fmaf(__uint_as_float(((unsigned)u[qq]) << 16), w, acc[qq]);
    }
    // history s <= g-2 folded in with float4 loads
    for (int s = jg; s < g - 1; s += 16) {
      const float4* fp = (const float4*)(a.FU + (size_t)(s*NB + b)*HH + i0 + il);
      float4 f0 = fp[0], f1 = fp[1];
      float al = al_l[s];
      acc[0] = fmaf(f0.x, al, acc[0]); acc[1] = fmaf(f0.y, al, acc[1]);
      acc[2] = fmaf(f0.z, al, acc[2]); acc[3] = fmaf(f0.w, al, acc[3]);
      acc[4] = fmaf(f1.x, al, acc[4]); acc[5] = fmaf(f1.y, al, acc[5]);
      acc[6] = fmaf(f1.z, al, acc[6]); acc[7] = fmaf(f1.w, al, acc[7]);
    }
    ((float4*)&sacc[jg][il])[0] = make_float4(acc[0],acc[1],acc[2],acc[3]);
    ((float4*)&sacc[jg][il])[1] = make_float4(acc[4],acc[5],acc[6],acc[7]);
    __syncthreads();
    if (tid < 128) {
      const int i = i0 + tid;
      float colsum = 0.f;
      #pragma unroll
      for (int r = 0; r < 16; r++) colsum += sacc[r][tid];
      if (g > 0) {
        const float m_cur  = a.stats[(g & 1)*NB*2 + b*2];
        const float sd_cur = a.stats[(g & 1)*NB*2 + b*2 + 1];
        const float m_pre  = a.stats[((g + 1) & 1)*NB*2 + b*2];
        const float sd_pre = a.stats[((g + 1) & 1)*NB*2 + b*2 + 1];
        float wpv = a.Wp[b*HH + i];
        float wv  = powf(cdec, (float)(g - 1)) * wpv;
        float tmp = (a.h1[(size_t)((g + 1) & 1)*NB*HH + b*HH + i] - m_pre*wv) / sd_pre;
        float post = (rh_l[i] - m_cur) / sd_cur;
        float coef = powf(cdec, -(float)g) * DTC * ev;
        float fu = coef * (post - tmp);
        a.FU[(size_t)((g - 1)*NB + b)*HH + i] = fu;
        a.Wp[b*HH + i] = wpv + a.sigv[b] * fu;
        colsum += al_l[g - 1] * fu;
      }
      a.h1[(size_t)(g & 1)*NB*HH + b*HH + i] = powf(cdec, (float)g) * colsum;
    }
  } else {
    // batch-tiled GEMM partials: m0 gh2 = W_h2h_hpc @ rp ; m1 gp2 = W_hh_pfc @ rp ; m2 gp3 = W_h2h_pfc @ rh
    const int gid = bid - 128;
    const int m = gid >> 5, sub = gid & 31, ic = sub >> 2, jc = sub & 3;
    const int j0 = jc*128, i0 = ic*64;
    const float* WT  = (m == 0) ? a.WThh : (m == 1) ? a.WTpp : a.WTph;
    const float* vec = (m == 2) ? (a.rh + (size_t)(g % 3)*NB*HH) : (a.rp + (size_t)(g & 1)*NB*HH);
    for (int k = 0; k < 16; k++) {
      int e = tid + k*256;
      int b2 = e >> 7, jl = e & 127;
      vl[jl*33 + b2] = vec[(size_t)b2*HH + j0 + jl];
    }
    __syncthreads();
    const int bb = tid & 31, ig = tid >> 5;
    const int ii = i0 + ig*8;
    float acc[8] = {0.f,0.f,0.f,0.f,0.f,0.f,0.f,0.f};
    for (int jl = 0; jl < 128; jl++) {
      float v = vl[jl*33 + bb];
      const float* wr = WT + (size_t)(j0 + jl)*HH + ii;
      #pragma unroll
      for (int qq = 0; qq < 8; qq++) acc[qq] += wr[qq] * v;
    }
    float* dst = a.gpart + (size_t)((m*4 + jc)*NB + bb)*HH + ii;
    #pragma unroll
    for (int qq = 0; qq < 8; qq++) dst[qq] = acc[qq];
  }
}

// ---------- per-step P2: state update / stats / logits / V,sigma / W_e partials / alphas ----------
__global__ __launch_bounds__(256) void k_p2(Args a) {
  const int g = a.g;
  const int bid = blockIdx.x;
  const int tid = threadIdx.x;
  const int t = g % TDIM, tri = g / TDIM;
  __shared__ float inpA[NB][NIN];
  __shared__ float rhn_l[HH];
  __shared__ float redm[28];
  __shared__ float vl[64*33];
  stage_inp_all(a, inpA);
  __syncthreads();
  if (bid < 32) {
    const int b = bid;
    const float m_cur  = a.stats[(g & 1)*NB*2 + b*2];
    const float sd_cur = a.stats[(g & 1)*NB*2 + b*2 + 1];
    float vals[7] = {0.f,0.f,0.f,0.f,0.f,0.f,0.f}; // pfv, sum(rhn), sumsq(rhn), lg0..3
    for (int kk = 0; kk < 2; kk++) {
      int ii = tid + kk*256;
      float rhn = calc_rhn(a, b, ii, inpA[b]);
      float rpn = calc_rpn(a, b, ii, inpA[b]);
      a.rh[(size_t)((g + 1) % 3)*NB*HH + b*HH + ii] = rhn;
      a.rp[(size_t)((g + 1) & 1)*NB*HH + b*HH + ii] = (t == 23) ? 0.f : rpn;
      float rhc = a.rh[(size_t)(g % 3)*NB*HH + b*HH + ii];
      float fv = (rhc - m_cur) / sd_cur;
      a.FV[(size_t)(g*NB + b)*HH + ii] = fv;
      vals[0] += fv; vals[1] += rhn; vals[2] += rhn*rhn;
      vals[3] += a.Wo[0*HH + ii]*rpn; vals[4] += a.Wo[1*HH + ii]*rpn;
      vals[5] += a.Wo[2*HH + ii]*rpn; vals[6] += a.Wo[3*HH + ii]*rpn;
    }
    // combined 7-way block reduction
    {
      const int lane = tid & 63, wv = tid >> 6;
      #pragma unroll
      for (int k = 0; k < 7; k++) {
        float v = vals[k];
        #pragma unroll
        for (int off = 32; off > 0; off >>= 1) v += __shfl_down(v, off, 64);
        if (lane == 0) redm[k*4 + wv] = v;
      }
      __syncthreads();
      #pragma unroll
      for (int k = 0; k < 7; k++)
        vals[k] = redm[k*4] + redm[k*4+1] + redm[k*4+2] + redm[k*4+3];
    }
    float sig = vals[0];
    float m2  = vals[1] / (float)HH;
    float sd2 = sqrtf(vals[2] / (float)HH - m2*m2 + EPSC);
    float L0 = vals[3] + a.Bo[0], L1 = vals[4] + a.Bo[1];
    float L2 = vals[5] + a.Bo[2], L3 = vals[6] + a.Bo[3];
    if (tid == 0) {
      a.sigv[b] = sig;
      a.stats[((g + 1) & 1)*NB*2 + b*2] = m2;
      a.stats[((g + 1) & 1)*NB*2 + b*2 + 1] = sd2;
      float sl0 = a.slog[b*4], sl1 = a.slog[b*4+1], sl2 = a.slog[b*4+2], sl3 = a.slog[b*4+3];
      float sp0 = a.sprob[b*4], sp1 = a.sprob[b*4+1], sp2 = a.sprob[b*4+2], sp3 = a.sprob[b*4+3];
      if (t >= 12 && t < 20) {
        sl0 += L0; sl1 += L1; sl2 += L2; sl3 += L3;
        float mx = fmaxf(fmaxf(L0, L1), fmaxf(L2, L3));
        float e0 = expf(L0 - mx), e1 = expf(L1 - mx), e2 = expf(L2 - mx), e3 = expf(L3 - mx);
        float es = e0 + e1 + e2 + e3;
        sp0 += e0/es; sp1 += e1/es; sp2 += e2/es; sp3 += e3/es;
      }
      float rwn, as0, as1, as2, as3;
      if (t == 19) {
        int am = 0; float bv = sp0;
        if (sp1 > bv) { bv = sp1; am = 1; }
        if (sp2 > bv) { bv = sp2; am = 2; }
        if (sp3 > bv) { bv = sp3; am = 3; }
        float corr = a.Y[(size_t)(b*4 + am)*NTRI + tri];
        rwn = (corr > 0.9f) ? 1.f : -1.f;
        as0 = (am == 0) ? 1.f : 0.f; as1 = (am == 1) ? 1.f : 0.f;
        as2 = (am == 2) ? 1.f : 0.f; as3 = (am == 3) ? 1.f : 0.f;
      } else {
        rwn = a.rwb[(g & 1)*NB + b];
        const float* ap = a.aselb + (size_t)((g & 1)*NB + b)*4;
        as0 = ap[0]; as1 = ap[1]; as2 = ap[2]; as3 = ap[3];
      }
      if (t == 23) {
        float* o = a.out + (size_t)tri*NB*4 + b*4;
        o[0] = sl0/8.f; o[1] = sl1/8.f; o[2] = sl2/8.f; o[3] = sl3/8.f;
        sl0 = sl1 = sl2 = sl3 = 0.f; sp0 = sp1 = sp2 = sp3 = 0.f;
        rwn = 0.f; as0 = as1 = as2 = as3 = 0.f;
      }
      a.slog[b*4] = sl0; a.slog[b*4+1] = sl1; a.slog[b*4+2] = sl2; a.slog[b*4+3] = sl3;
      a.sprob[b*4] = sp0; a.sprob[b*4+1] = sp1; a.sprob[b*4+2] = sp2; a.sprob[b*4+3] = sp3;
      a.rwb[((g + 1) & 1)*NB + b] = rwn;
      float* an = a.aselb + (size_t)(((g + 1) & 1)*NB + b)*4;
      an[0] = as0; an[1] = as1; an[2] = as2; an[3] = as3;
    }
  } else if (bid < 64) {
    // W_e GEMV partials over j-chunks (true rp_new recomputed; no t==23 reset here)
    const int hb = bid - 32;
    const int jc = hb >> 2, icc = hb & 3;
    const int j0 = jc*64;
    for (int k = 0; k < 8; k++) {
      int e = tid + k*256;
      int b2 = e >> 6, jl = e & 63;
      vl[jl*33 + b2] = calc_rpn(a, b2, j0 + jl, inpA[b2]);
    }
    __syncthreads();
    const int bb = tid & 31, ig = tid >> 5;
    const int ii = icc*128 + ig*16;
    float acc[16];
    #pragma unroll
    for (int q = 0; q < 16; q++) acc[q] = 0.f;
    for (int jl = 0; jl < 64; jl++) {
      float v = vl[jl*33 + bb];
      const float* wr = a.WTe + (size_t)(j0 + jl)*HH + ii;
      #pragma unroll
      for (int q = 0; q < 16; q++) acc[q] += wr[q] * v;
    }
    float* dst = a.hepart + (size_t)(jc*NB + bb)*HH + ii;
    #pragma unroll
    for (int q = 0; q < 16; q++) dst[q] = acc[q];
  } else {
    // alpha dots for next step: alpha[s] = v_s . rh_{g+1}, s = 0..g  (s==g computed directly)
    const int b = bid - 64;
    for (int ii = tid; ii < HH; ii += 256) rhn_l[ii] = calc_rhn(a, b, ii, inpA[b]);
    __syncthreads();
    const int lane = tid & 63, wv = tid >> 6;
    const float m_cur  = a.stats[(g & 1)*NB*2 + b*2];
    const float sd_cur = a.stats[(g & 1)*NB*2 + b*2 + 1];
    const float* rhc = a.rh + (size_t)(g % 3)*NB*HH + b*HH;
    for (int s = wv; s <= g; s += 4) {
      float p = 0.f;
      if (s < g) {
        const float* V = a.FV + (size_t)(s*NB + b)*HH;
        for (int jj = lane; jj < HH; jj += 64) p += V[jj] * rhn_l[jj];
      } else {
        for (int jj = lane; jj < HH; jj += 64) p += ((rhc[jj] - m_cur)/sd_cur) * rhn_l[jj];
      }
      #pragma unroll
      for (int off = 32; off > 0; off >>= 1) p += __shfl_down(p, off, 64);
      if (lane == 0) a.alpha[b*GTOT + s] = p;
    }
  }
}

extern "C" void kernel_launch(void* const* d_in, const int* in_sizes, int n_in,
                              void* d_out, int out_size, void* d_ws, size_t ws_size,
                              hipStream_t stream) {
  (void)in_sizes; (void)n_in; (void)out_size; (void)ws_size;
  Args a;
  a.X     = (const float*)d_in[0];
  a.Y     = (const float*)d_in[1];
  a.A     = (const float*)d_in[2];
  a.RH0   = (const float*)d_in[3];
  a.Wihp  = (const float*)d_in[5];
  a.Whhp  = (const float*)d_in[6];
  a.Bp    = (const float*)d_in[7];
  a.Wh2hp = (const float*)d_in[8];
  a.Wihh  = (const float*)d_in[9];
  a.Wh2hh = (const float*)d_in[10];
  a.Lp    = (const float*)d_in[11];
  a.We    = (const float*)d_in[12];
  a.Be    = (const float*)d_in[13];
  a.Wpe   = (const float*)d_in[14];
  a.Bpe   = (const float*)d_in[15];
  a.Wo    = (const float*)d_in[16];
  a.Bo    = (const float*)d_in[17];
  char* w = (char*)d_ws;
  auto take = [&](size_t n) { char* p = w; w += (n + 255) & ~(size_t)255; return p; };
  a.A0T    = (bf16*)take((size_t)NB*HH*HH*sizeof(bf16));
  a.WThh   = (float*)take((size_t)HH*HH*4);
  a.WTpp   = (float*)take((size_t)HH*HH*4);
  a.WTph   = (float*)take((size_t)HH*HH*4);
  a.WTe    = (float*)take((size_t)HH*HH*4);
  a.WTih_h = (float*)take((size_t)NIN*HH*4);
  a.WTih_p = (float*)take((size_t)NIN*HH*4);
  a.rh     = (float*)take((size_t)3*NB*HH*4);
  a.rp     = (float*)take((size_t)2*NB*HH*4);
  a.h1     = (float*)take((size_t)2*NB*HH*4);
  a.Wp     = (float*)take((size_t)NB*HH*4);
  a.FU     = (float*)take((size_t)GTOT*NB*HH*4);
  a.FV     = (float*)take((size_t)GTOT*NB*HH*4);
  a.alpha  = (float*)take((size_t)NB*GTOT*4);
  a.gpart  = (float*)take((size_t)12*NB*HH*4);
  a.hepart = (float*)take((size_t)8*NB*HH*4);
  a.stats  = (float*)take((size_t)2*NB*2*4);
  a.sigv   = (float*)take((size_t)NB*4);
  a.rwb    = (float*)take((size_t)2*NB*4);
  a.aselb  = (float*)take((size_t)2*NB*4*4);
  a.slog   = (float*)take((size_t)NB*4*4);
  a.sprob  = (float*)take((size_t)NB*4*4);
  a.out    = (float*)d_out;
  a.g = 0;
  k_prep_t<<<dim3(9216), dim3(256), 0, stream>>>(a);
  k_prep_i<<<dim3(163),  dim3(256), 0, stream>>>(a);
  for (int g = 0; g < GTOT; g++) {
    a.g = g;
    k_p1<<<dim3(224), dim3(256), 0, stream>>>(a);
    k_p2<<<dim3(96),  dim3(256), 0, stream>>>(a);
  }
}